// Round 6
// baseline (1063.319 us; speedup 1.0000x reference)
//
#include <hip/hip_runtime.h>
#include <hip/hip_bf16.h>
#include <math.h>

typedef float f32x4 __attribute__((ext_vector_type(4)));
typedef short s16x8 __attribute__((ext_vector_type(8)));
typedef float v2f   __attribute__((ext_vector_type(2)));

// ---- workspace layout (bytes) ---- total < 1 MB
static const long long OFF_W2  = 0LL;        // bf16 [9][128][64]  = 147,456 B
static const long long OFF_W3  = 147456LL;   // bf16 [9][256][128] = 589,824 B
static const long long OFF_AB1 = 737280LL;   // float2 [64]
static const long long OFF_AB2 = 737792LL;   // float2 [128]
static const long long OFF_AB3 = 738816LL;   // float2 [256]
static const long long OFF_Q   = 740864LL;   // float  [8]

__device__ inline unsigned short f2bfu(float f) {
    __hip_bfloat16 h = __float2bfloat16(f);
    unsigned short u;
    __builtin_memcpy(&u, &h, 2);
    return u;
}

__device__ inline unsigned pack2bf(float a, float b) {
    __hip_bfloat162 h = __float22bfloat162_rn(make_float2(a, b));
    unsigned u;
    __builtin_memcpy(&u, &h, 4);
    return u;
}

// ---------------- prep: weight transpose to [kykx][oc][ic] bf16 + BN folding + fc fold ----------------
__global__ __launch_bounds__(256) void prep_k(
    const float* __restrict__ c2w, const float* __restrict__ c3w,
    const float* __restrict__ c1b, const float* __restrict__ g1, const float* __restrict__ b1,
    const float* __restrict__ m1, const float* __restrict__ v1,
    const float* __restrict__ c2b, const float* __restrict__ g2, const float* __restrict__ b2,
    const float* __restrict__ m2, const float* __restrict__ v2,
    const float* __restrict__ c3b, const float* __restrict__ g3, const float* __restrict__ b3,
    const float* __restrict__ m3, const float* __restrict__ v3,
    const float* __restrict__ fc1b, const float* __restrict__ qp,
    const float* __restrict__ fc2w, const float* __restrict__ fc2b,
    const float* __restrict__ fc3w, const float* __restrict__ fc3b,
    short* __restrict__ wT2, short* __restrict__ wT3,
    float2* __restrict__ ab1, float2* __restrict__ ab2, float2* __restrict__ ab3,
    float* __restrict__ qc)
{
    int tid = blockIdx.x * 256 + threadIdx.x;
    if (tid < 73728) {                       // 9*128*64
        int ic = tid & 63, oc = (tid >> 6) & 127, k = tid >> 13;
        wT2[tid] = (short)f2bfu(c2w[(oc * 64 + ic) * 9 + k]);
    }
    if (tid < 294912) {                      // 9*256*128
        int ic = tid & 127, oc = (tid >> 7) & 255, k = tid >> 15;
        wT3[tid] = (short)f2bfu(c3w[(oc * 128 + ic) * 9 + k]);
    }
    if (tid < 64) {
        float s = g1[tid] / sqrtf(v1[tid] + 1e-5f);
        ab1[tid] = make_float2(s, (c1b[tid] - m1[tid]) * s + b1[tid]);
    } else if (tid < 192) {
        int c = tid - 64;
        float s = g2[c] / sqrtf(v2[c] + 1e-5f);
        ab2[c] = make_float2(s, (c2b[c] - m2[c]) * s + b2[c]);
    } else if (tid < 448) {
        int c = tid - 192;
        float s = g3[c] / sqrtf(v3[c] + 1e-5f);
        ab3[c] = make_float2(s, (c3b[c] - m3[c]) * s + b3[c]);
    } else if (tid == 448) {
        float A0 = 0.f, A1 = 0.f, B0 = 0.f, B1 = 0.f;
        for (int k = 0; k < 128; ++k) {
            float f2 = fc2w[k], fb = fc2b[k];
            A0 += fc3w[k] * f2;        B0 += fc3w[k] * fb;
            A1 += fc3w[128 + k] * f2;  B1 += fc3w[128 + k] * fb;
        }
        qc[0] = A0; qc[1] = A1;
        qc[2] = B0 + fc3b[0]; qc[3] = B1 + fc3b[1];
        qc[4] = cosf(qp[1]);  qc[5] = fc1b[1];
    }
}

// ---------------- fused: conv1 -> conv2(MFMA) -> conv3(MFMA) -> tail. One block per image. ----------------
// Register budget (unified VGPR+AGPR, 256/wave at launch_bounds(256,2)): stage B accs = 112 AGPR,
// A-prefetch dbuf +32 VGPR, arch ~100 -> ~212 total. 232 spilled in round 4 -- keep below.
// xs3 is a SEPARATE LDS array (no alias) -> no mid-stage drain barrier / re-zero.
__global__ __launch_bounds__(256, 2) void fused_k(
    const float* __restrict__ x, const float* __restrict__ c1w,
    const float2* __restrict__ ab1, const float2* __restrict__ ab2,
    const float2* __restrict__ ab3,
    const short* __restrict__ wT2, const short* __restrict__ wT3,
    const float* __restrict__ fc1w, const float* __restrict__ qc,
    float* __restrict__ out)
{
    __shared__ short smem2[16 * 16 * 64 + 128]; // conv2 tile [y][x][8 blk][8 ic] swizzled + OOB pad (33,024 B)
    __shared__ short xs3[8 * 8 * 128 + 256];    // conv3 tile [y][x][16 blk][8 ic] swizzled + OOB pad (16,896 B)
    __shared__ float xt[30][32];                // padded 28x28 input at [1..28][1..28]            (3,840 B)
    __shared__ float red[4];

    int b = blockIdx.x, t = threadIdx.x;

    // ---- zero-init (conv padding + OOB pads must be deterministic) ----
    for (int i = t; i < 8256; i += 256) ((unsigned*)smem2)[i] = 0u;
    for (int i = t; i < 4224; i += 256) ((unsigned*)xs3)[i] = 0u;
    for (int i = t; i < 960;  i += 256) ((float*)xt)[i] = 0.f;
    __syncthreads();

    // ---- stage A: load input; conv1 (packed fp32) + BN + ReLU + 2x2 pool -> smem2 ----
    for (int i = t; i < 784; i += 256) xt[i / 28 + 1][i % 28 + 1] = x[b * 784 + i];

    int og4 = t & 15;                        // 16 groups of 4 output channels (bank-spread store halves)
    int oc0a = og4 * 4;
    float wr[4][9];
    float2 abr[4];
#pragma unroll
    for (int c = 0; c < 4; ++c) {
#pragma unroll
        for (int k = 0; k < 9; ++k) wr[c][k] = c1w[(oc0a + c) * 9 + k];
        abr[c] = ab1[oc0a + c];
    }
    __syncthreads();

    int posb = t >> 4;                       // 0..15
    for (int p = posb; p < 196; p += 16) {
        int py = p / 14, px = p % 14;
        int y0 = 2 * py, x0 = 2 * px;        // x0 even -> 8B-aligned v2f loads
        v2f rowv[4][2];
#pragma unroll
        for (int i = 0; i < 4; ++i) {
            rowv[i][0] = *(const v2f*)&xt[y0 + i][x0];
            rowv[i][1] = *(const v2f*)&xt[y0 + i][x0 + 2];
        }
        float pv[4];
#pragma unroll
        for (int c = 0; c < 4; ++c) {
            v2f a0 = {0.f, 0.f}, a1 = {0.f, 0.f};   // (out00,out01), (out10,out11)
#pragma unroll
            for (int ky = 0; ky < 3; ++ky) {
                float w0 = wr[c][ky * 3 + 0], w1 = wr[c][ky * 3 + 1], w2 = wr[c][ky * 3 + 2];
                v2f p00 = rowv[ky][0],     p01 = rowv[ky][1];
                v2f p10 = rowv[ky + 1][0], p11 = rowv[ky + 1][1];
                v2f q0; q0.x = p00.y; q0.y = p01.x;
                v2f q1; q1.x = p10.y; q1.y = p11.x;
                a0 += p00 * w0; a0 += q0 * w1; a0 += p01 * w2;
                a1 += p10 * w0; a1 += q1 * w1; a1 += p11 * w2;
            }
            float aa = abr[c].x, bb = abr[c].y;
            v2f r0 = a0 * aa + bb;
            v2f r1 = a1 * aa + bb;
            pv[c] = fmaxf(fmaxf(fmaxf(r0.x, r0.y), fmaxf(r1.x, r1.y)), 0.f);
        }
        uint2 pk;
        pk.x = pack2bf(pv[0], pv[1]);
        pk.y = pack2bf(pv[2], pv[3]);
        int blk = (og4 >> 1) ^ ((px + 1) & 7);   // XOR swizzle by padded column
        *(uint2*)&smem2[((((py + 1) * 16) + (px + 1)) * 8 + blk) * 8 + (og4 & 1) * 4] = pk;
    }
    __syncthreads();

    // ---- stage B: conv2 (64->128) MFMA. Waves: (oc-half oh) x (pooled-col-half cb). ----
    int lane = t & 63, wid = t >> 6;
    int quad = lane >> 4, n16 = lane & 15;
    int dy = n16 >> 3, lx = n16 & 7;
    int cb = wid >> 1;                       // 0: output cols 1..8 ; 1: cols 9..16
    int oh = wid & 1;                        // oc half (64 ocs)

    {
        f32x4 acc[4][7];                     // [ml(16oc)][ry(pooled row)]  = 112 AGPR
        f32x4 z = {0.f, 0.f, 0.f, 0.f};
#pragma unroll
        for (int ml = 0; ml < 4; ++ml)
#pragma unroll
            for (int ry = 0; ry < 7; ++ry) acc[ml][ry] = z;

        const short* aB0 = wT2 + oh * 4096 + n16 * 64 + quad * 8;
        s16x8 Ac[4], An[4];
#pragma unroll
        for (int ml = 0; ml < 4; ++ml) Ac[ml] = *(const s16x8*)(aB0 + ml * 1024);

#pragma unroll 1
        for (int it = 0; it < 18; ++it) {
            int kykx = it >> 1, kk = it & 1;
            int ky = kykx / 3, kx = kykx - 3 * ky;
            int y0 = dy + ky;
            int xc = lx + kx + cb * 8;       // padded input col (garbage lanes lx>=6@cb=1 discarded)
            int blk = (kk * 4 + quad) ^ (xc & 7);
            const short* bp = &smem2[((y0 * 16 + xc) * 8 + blk) * 8];
            int itn = (it < 17) ? it + 1 : 0;
            const short* an = aB0 + (itn >> 1) * 8192 + (itn & 1) * 32;
#pragma unroll
            for (int ml = 0; ml < 4; ++ml) An[ml] = *(const s16x8*)(an + ml * 1024);
#pragma unroll
            for (int ry = 0; ry < 7; ++ry) {
                s16x8 B = *(const s16x8*)(bp + ry * 2048);   // immediate offsets
#pragma unroll
                for (int ml = 0; ml < 4; ++ml)
                    acc[ml][ry] = __builtin_amdgcn_mfma_f32_16x16x32_bf16(Ac[ml], B, acc[ml][ry], 0, 0, 0);
            }
#pragma unroll
            for (int ml = 0; ml < 4; ++ml) Ac[ml] = An[ml];
        }

        // epilogue: affine -> pool (shfl 1,8) -> ReLU -> store into xs3 (no barrier needed: disjoint array)
        int m = lx >> 1;
        int xp = cb * 4 + m;
        bool keep = (dy == 0) && ((lx & 1) == 0) && (xp < 7);
#pragma unroll
        for (int ml = 0; ml < 4; ++ml) {
            int oc0 = oh * 64 + ml * 16 + quad * 4;
            float2 abv[4];
#pragma unroll
            for (int r = 0; r < 4; ++r) abv[r] = ab2[oc0 + r];
#pragma unroll
            for (int ry = 0; ry < 7; ++ry) {
                float pv[4];
#pragma unroll
                for (int r = 0; r < 4; ++r) {
                    float v = acc[ml][ry][r] * abv[r].x + abv[r].y;
                    v = fmaxf(v, __shfl_xor(v, 1));
                    v = fmaxf(v, __shfl_xor(v, 8));
                    pv[r] = fmaxf(v, 0.f);
                }
                if (keep) {
                    uint2 pk;
                    pk.x = pack2bf(pv[0], pv[1]);
                    pk.y = pack2bf(pv[2], pv[3]);
                    int blk3 = (oc0 >> 3) ^ (((xp + 1) & 7) << 1);
                    *(uint2*)&xs3[(((ry + 1) * 8 + (xp + 1)) * 16 + blk3) * 8 + (oc0 & 7)] = pk;
                }
            }
        }
    }
    __syncthreads();

    // ---- stage C: conv3 (128->256) MFMA. Waves: oc-quarter each, all 3 pooled rows. 48 AGPR. ----
    int oq = wid;                            // oc quarter (64 ocs, 4 frags of 16)

    f32x4 acc3[4][3];
    {
        f32x4 z = {0.f, 0.f, 0.f, 0.f};
#pragma unroll
        for (int ml = 0; ml < 4; ++ml)
#pragma unroll
            for (int nt = 0; nt < 3; ++nt) acc3[ml][nt] = z;
    }

    {
        const short* aC0 = wT3 + oq * 8192 + n16 * 128 + quad * 8;
        s16x8 Ac[4], An[4];
#pragma unroll
        for (int ml = 0; ml < 4; ++ml) Ac[ml] = *(const s16x8*)(aC0 + ml * 2048);

#pragma unroll 1
        for (int it = 0; it < 36; ++it) {
            int kykx = it >> 2, kk = it & 3;
            int ky = kykx / 3, kx = kykx - 3 * ky;
            int y0 = dy + ky;
            int x0 = lx + kx;                // garbage lanes lx>=6 discarded
            int blk = (kk * 4 + quad) ^ ((x0 & 7) << 1);
            const short* bp = &xs3[((y0 * 8 + x0) * 16 + blk) * 8];
            int itn = (it < 35) ? it + 1 : 0;
            const short* an = aC0 + (itn >> 2) * 32768 + (itn & 3) * 32;
#pragma unroll
            for (int ml = 0; ml < 4; ++ml) An[ml] = *(const s16x8*)(an + ml * 2048);
            s16x8 B0 = *(const s16x8*)(bp);            // pooled row 0 (y_in = y0)
            s16x8 B1 = *(const s16x8*)(bp + 2048);     // pooled row 1 (y_in = y0+2)
            s16x8 B2 = *(const s16x8*)(bp + 4096);     // pooled row 2 (y_in = y0+4)
#pragma unroll
            for (int ml = 0; ml < 4; ++ml) {
                acc3[ml][0] = __builtin_amdgcn_mfma_f32_16x16x32_bf16(Ac[ml], B0, acc3[ml][0], 0, 0, 0);
                acc3[ml][1] = __builtin_amdgcn_mfma_f32_16x16x32_bf16(Ac[ml], B1, acc3[ml][1], 0, 0, 0);
                acc3[ml][2] = __builtin_amdgcn_mfma_f32_16x16x32_bf16(Ac[ml], B2, acc3[ml][2], 0, 0, 0);
            }
#pragma unroll
            for (int ml = 0; ml < 4; ++ml) Ac[ml] = An[ml];
        }
    }

    // epilogue: affine -> pool -> relu -> dot with fc1_w row 1
    float vacc = 0.f;
    {
        int m = lx >> 1;
        bool keep = (dy == 0) && ((lx & 1) == 0) && (m < 3);
        const float* fc1w1 = fc1w + 2304;    // row 1 (only row that matters)
#pragma unroll
        for (int ml = 0; ml < 4; ++ml) {
            int oc0 = oq * 64 + ml * 16 + quad * 4;
            float2 abv[4];
#pragma unroll
            for (int r = 0; r < 4; ++r) abv[r] = ab3[oc0 + r];
#pragma unroll
            for (int nt = 0; nt < 3; ++nt) {
#pragma unroll
                for (int r = 0; r < 4; ++r) {
                    float v = acc3[ml][nt][r] * abv[r].x + abv[r].y;
                    v = fmaxf(v, __shfl_xor(v, 1));
                    v = fmaxf(v, __shfl_xor(v, 8));
                    v = fmaxf(v, 0.f);
                    if (keep) vacc += v * fc1w1[(oc0 + r) * 9 + nt * 3 + m];
                }
            }
        }
    }
#pragma unroll
    for (int s = 1; s < 64; s <<= 1) vacc += __shfl_xor(vacc, s);
    if (lane == 0) red[wid] = vacc;
    __syncthreads();
    if (t == 0) {
        float v = red[0] + red[1] + red[2] + red[3] + qc[5];
        // quantum circuit closed form: <Z0 Z1> = cos(h[:,1]) * cos(qp[1])
        float q = cosf(v) * qc[4];
        float l0 = q * qc[0] + qc[2];
        float l1 = q * qc[1] + qc[3];
        float mx = fmaxf(l0, l1);
        float lse = mx + logf(__expf(l0 - mx) + __expf(l1 - mx));
        out[b * 2 + 0] = l0 - lse;
        out[b * 2 + 1] = l1 - lse;
    }
}

extern "C" void kernel_launch(void* const* d_in, const int* in_sizes, int n_in,
                              void* d_out, int out_size, void* d_ws, size_t ws_size,
                              hipStream_t stream)
{
    const float* x    = (const float*)d_in[0];
    const float* c1w  = (const float*)d_in[1];
    const float* c1b  = (const float*)d_in[2];
    const float* c2w  = (const float*)d_in[3];
    const float* c2b  = (const float*)d_in[4];
    const float* c3w  = (const float*)d_in[5];
    const float* c3b  = (const float*)d_in[6];
    const float* g1   = (const float*)d_in[7];
    const float* b1   = (const float*)d_in[8];
    const float* m1   = (const float*)d_in[9];
    const float* v1   = (const float*)d_in[10];
    const float* g2   = (const float*)d_in[11];
    const float* b2   = (const float*)d_in[12];
    const float* m2   = (const float*)d_in[13];
    const float* v2   = (const float*)d_in[14];
    const float* g3   = (const float*)d_in[15];
    const float* b3   = (const float*)d_in[16];
    const float* m3   = (const float*)d_in[17];
    const float* v3   = (const float*)d_in[18];
    const float* fc1w = (const float*)d_in[19];
    const float* fc1b = (const float*)d_in[20];
    const float* qp   = (const float*)d_in[21];
    const float* fc2w = (const float*)d_in[22];
    const float* fc2b = (const float*)d_in[23];
    const float* fc3w = (const float*)d_in[24];
    const float* fc3b = (const float*)d_in[25];
    float* out = (float*)d_out;
    char* ws = (char*)d_ws;

    short*  wT2 = (short*)(ws + OFF_W2);
    short*  wT3 = (short*)(ws + OFF_W3);
    float2* ab1 = (float2*)(ws + OFF_AB1);
    float2* ab2 = (float2*)(ws + OFF_AB2);
    float2* ab3 = (float2*)(ws + OFF_AB3);
    float*  qc  = (float*)(ws + OFF_Q);

    int B = in_sizes[0] / 784;               // 8192

    prep_k<<<1152, 256, 0, stream>>>(c2w, c3w, c1b, g1, b1, m1, v1,
                                     c2b, g2, b2, m2, v2, c3b, g3, b3, m3, v3,
                                     fc1b, qp, fc2w, fc2b, fc3w, fc3b,
                                     wT2, wT3, ab1, ab2, ab3, qc);
    fused_k<<<B, 256, 0, stream>>>(x, c1w, ab1, ab2, ab3, wT2, wT3, fc1w, qc, out);
}

// Round 7
// 1056.816 us; speedup vs baseline: 1.0062x; 1.0062x over previous
//
#include <hip/hip_runtime.h>
#include <hip/hip_bf16.h>
#include <math.h>

typedef float f32x4 __attribute__((ext_vector_type(4)));
typedef short s16x8 __attribute__((ext_vector_type(8)));
typedef float v2f   __attribute__((ext_vector_type(2)));

// ---- workspace layout (bytes) ---- total < 1 MB
static const long long OFF_W2  = 0LL;        // bf16 [9][128][64]  = 147,456 B
static const long long OFF_W3  = 147456LL;   // bf16 [9][256][128] = 589,824 B
static const long long OFF_AB1 = 737280LL;   // float2 [64]
static const long long OFF_AB2 = 737792LL;   // float2 [128]
static const long long OFF_AB3 = 738816LL;   // float2 [256]
static const long long OFF_Q   = 740864LL;   // float  [8]

__device__ inline unsigned short f2bfu(float f) {
    __hip_bfloat16 h = __float2bfloat16(f);
    unsigned short u;
    __builtin_memcpy(&u, &h, 2);
    return u;
}

__device__ inline unsigned pack2bf(float a, float b) {
    __hip_bfloat162 h = __float22bfloat162_rn(make_float2(a, b));
    unsigned u;
    __builtin_memcpy(&u, &h, 4);
    return u;
}

// ---------------- prep: weight transpose to [kykx][oc][ic] bf16 + BN folding + fc fold ----------------
__global__ __launch_bounds__(256) void prep_k(
    const float* __restrict__ c2w, const float* __restrict__ c3w,
    const float* __restrict__ c1b, const float* __restrict__ g1, const float* __restrict__ b1,
    const float* __restrict__ m1, const float* __restrict__ v1,
    const float* __restrict__ c2b, const float* __restrict__ g2, const float* __restrict__ b2,
    const float* __restrict__ m2, const float* __restrict__ v2,
    const float* __restrict__ c3b, const float* __restrict__ g3, const float* __restrict__ b3,
    const float* __restrict__ m3, const float* __restrict__ v3,
    const float* __restrict__ fc1b, const float* __restrict__ qp,
    const float* __restrict__ fc2w, const float* __restrict__ fc2b,
    const float* __restrict__ fc3w, const float* __restrict__ fc3b,
    short* __restrict__ wT2, short* __restrict__ wT3,
    float2* __restrict__ ab1, float2* __restrict__ ab2, float2* __restrict__ ab3,
    float* __restrict__ qc)
{
    int tid = blockIdx.x * 256 + threadIdx.x;
    if (tid < 73728) {                       // 9*128*64
        int ic = tid & 63, oc = (tid >> 6) & 127, k = tid >> 13;
        wT2[tid] = (short)f2bfu(c2w[(oc * 64 + ic) * 9 + k]);
    }
    if (tid < 294912) {                      // 9*256*128
        int ic = tid & 127, oc = (tid >> 7) & 255, k = tid >> 15;
        wT3[tid] = (short)f2bfu(c3w[(oc * 128 + ic) * 9 + k]);
    }
    if (tid < 64) {
        float s = g1[tid] / sqrtf(v1[tid] + 1e-5f);
        ab1[tid] = make_float2(s, (c1b[tid] - m1[tid]) * s + b1[tid]);
    } else if (tid < 192) {
        int c = tid - 64;
        float s = g2[c] / sqrtf(v2[c] + 1e-5f);
        ab2[c] = make_float2(s, (c2b[c] - m2[c]) * s + b2[c]);
    } else if (tid < 448) {
        int c = tid - 192;
        float s = g3[c] / sqrtf(v3[c] + 1e-5f);
        ab3[c] = make_float2(s, (c3b[c] - m3[c]) * s + b3[c]);
    } else if (tid == 448) {
        float A0 = 0.f, A1 = 0.f, B0 = 0.f, B1 = 0.f;
        for (int k = 0; k < 128; ++k) {
            float f2 = fc2w[k], fb = fc2b[k];
            A0 += fc3w[k] * f2;        B0 += fc3w[k] * fb;
            A1 += fc3w[128 + k] * f2;  B1 += fc3w[128 + k] * fb;
        }
        qc[0] = A0; qc[1] = A1;
        qc[2] = B0 + fc3b[0]; qc[3] = B1 + fc3b[1];
        qc[4] = cosf(qp[1]);  qc[5] = fc1b[1];
    }
}

// ---------------- fused: conv1 -> conv2(MFMA) -> conv3(MFMA) -> tail. One block per image. ----------------
// LDS budget: 3 blocks/CU requires total <= 54,613 B (163,840/3). R6's separate xt (3,840 B) pushed
// 54,272+slop over the edge -> 2 blocks (occ 23.7%). Fix: xt ALIASES smem2 rows 0+15 (which are only
// zero-padding for stage B); rows re-zeroed after conv1. Total = 33,024+16,896+16 = 49,936 B.
// Register note: launch_bounds(256,2); VGPR ~88 + 112 AGPR acc. 232 spilled in round 4 -- keep lean.
#define XT(r, c) (((float*)smem2)[(r) * 32 + (c) + ((r) < 16 ? 0 : 7168)])
__global__ __launch_bounds__(256, 2) void fused_k(
    const float* __restrict__ x, const float* __restrict__ c1w,
    const float2* __restrict__ ab1, const float2* __restrict__ ab2,
    const float2* __restrict__ ab3,
    const short* __restrict__ wT2, const short* __restrict__ wT3,
    const float* __restrict__ fc1w, const float* __restrict__ qc,
    float* __restrict__ out)
{
    __shared__ short smem2[16 * 16 * 64 + 128]; // conv2 tile [y][x][8 blk][8 ic] swizzled + OOB pad (33,024 B)
                                                // rows 0,15 double as xt (padded 28x28 fp32) during stage A
    __shared__ short xs3[8 * 8 * 128 + 256];    // conv3 tile [y][x][16 blk][8 ic] swizzled + OOB pad (16,896 B)
    __shared__ float red[4];

    int b = blockIdx.x, t = threadIdx.x;

    // ---- init-zero: xt region (= smem2 rows 0,15), xs3, smem2 x-pad cols 0/15 of rows 1..14, OOB tail ----
    for (int i = t; i < 960; i += 256) { int r = i >> 5, c = i & 31; XT(r, c) = 0.f; }
    for (int i = t; i < 4224; i += 256) ((unsigned*)xs3)[i] = 0u;
    for (int i = t; i < 896; i += 256) {     // 14 rows x 2 pad-cols x 32 dwords
        int seg = i >> 5, d = i & 31;
        int row = (seg >> 1) + 1, xcol = (seg & 1) * 15;
        ((unsigned*)smem2)[(row * 16 + xcol) * 32 + d] = 0u;
    }
    if (t < 64) ((unsigned*)smem2)[8192 + t] = 0u;   // OOB tail (shorts 16384..16512)
    __syncthreads();

    // ---- stage A: load input into xt; conv1 (packed fp32) + BN + ReLU + 2x2 pool -> smem2 rows 1..14 ----
    for (int i = t; i < 784; i += 256) XT(i / 28 + 1, i % 28 + 1) = x[b * 784 + i];

    int og4 = t & 15;                        // 16 groups of 4 output channels (bank-spread store halves)
    int oc0a = og4 * 4;
    float wr[4][9];
    float2 abr[4];
#pragma unroll
    for (int c = 0; c < 4; ++c) {
#pragma unroll
        for (int k = 0; k < 9; ++k) wr[c][k] = c1w[(oc0a + c) * 9 + k];
        abr[c] = ab1[oc0a + c];
    }
    __syncthreads();

    int posb = t >> 4;                       // 0..15
    for (int p = posb; p < 196; p += 16) {
        int py = p / 14, px = p % 14;
        int y0 = 2 * py, x0 = 2 * px;        // x0 even -> 8B-aligned v2f loads
        v2f rowv[4][2];
#pragma unroll
        for (int i = 0; i < 4; ++i) {
            rowv[i][0] = *(const v2f*)&XT(y0 + i, x0);
            rowv[i][1] = *(const v2f*)&XT(y0 + i, x0 + 2);
        }
        float pv[4];
#pragma unroll
        for (int c = 0; c < 4; ++c) {
            v2f a0 = {0.f, 0.f}, a1 = {0.f, 0.f};   // (out00,out01), (out10,out11)
#pragma unroll
            for (int ky = 0; ky < 3; ++ky) {
                float w0 = wr[c][ky * 3 + 0], w1 = wr[c][ky * 3 + 1], w2 = wr[c][ky * 3 + 2];
                v2f p00 = rowv[ky][0],     p01 = rowv[ky][1];
                v2f p10 = rowv[ky + 1][0], p11 = rowv[ky + 1][1];
                v2f q0; q0.x = p00.y; q0.y = p01.x;
                v2f q1; q1.x = p10.y; q1.y = p11.x;
                a0 += p00 * w0; a0 += q0 * w1; a0 += p01 * w2;
                a1 += p10 * w0; a1 += q1 * w1; a1 += p11 * w2;
            }
            float aa = abr[c].x, bb = abr[c].y;
            v2f r0 = a0 * aa + bb;
            v2f r1 = a1 * aa + bb;
            pv[c] = fmaxf(fmaxf(fmaxf(r0.x, r0.y), fmaxf(r1.x, r1.y)), 0.f);
        }
        uint2 pk;
        pk.x = pack2bf(pv[0], pv[1]);
        pk.y = pack2bf(pv[2], pv[3]);
        int blk = (og4 >> 1) ^ ((px + 1) & 7);   // XOR swizzle by padded column
        *(uint2*)&smem2[((((py + 1) * 16) + (px + 1)) * 8 + blk) * 8 + (og4 & 1) * 4] = pk;
    }
    __syncthreads();

    // ---- restore zero padding in rows 0,15 (xt is dead) ----
    for (int i = t; i < 1024; i += 256)
        ((unsigned*)smem2)[(i >> 9) * 7680 + (i & 511)] = 0u;   // dwords [0..512) and [7680..8192)
    __syncthreads();

    // ---- stage B: conv2 (64->128) MFMA. Waves: (oc-half oh) x (pooled-col-half cb). ----
    int lane = t & 63, wid = t >> 6;
    int quad = lane >> 4, n16 = lane & 15;
    int dy = n16 >> 3, lx = n16 & 7;
    int cb = wid >> 1;                       // 0: output cols 1..8 ; 1: cols 9..16
    int oh = wid & 1;                        // oc half (64 ocs)

    {
        f32x4 acc[4][7];                     // [ml(16oc)][ry(pooled row)]  = 112 AGPR
        f32x4 z = {0.f, 0.f, 0.f, 0.f};
#pragma unroll
        for (int ml = 0; ml < 4; ++ml)
#pragma unroll
            for (int ry = 0; ry < 7; ++ry) acc[ml][ry] = z;

        const short* aB0 = wT2 + oh * 4096 + n16 * 64 + quad * 8;
        s16x8 Ac[4], An[4];
#pragma unroll
        for (int ml = 0; ml < 4; ++ml) Ac[ml] = *(const s16x8*)(aB0 + ml * 1024);

#pragma unroll 1
        for (int it = 0; it < 18; ++it) {
            int kykx = it >> 1, kk = it & 1;
            int ky = kykx / 3, kx = kykx - 3 * ky;
            int y0 = dy + ky;
            int xc = lx + kx + cb * 8;       // padded input col (garbage lanes lx>=6@cb=1 discarded)
            int blk = (kk * 4 + quad) ^ (xc & 7);
            const short* bp = &smem2[((y0 * 16 + xc) * 8 + blk) * 8];
            int itn = (it < 17) ? it + 1 : 0;
            const short* an = aB0 + (itn >> 1) * 8192 + (itn & 1) * 32;
#pragma unroll
            for (int ml = 0; ml < 4; ++ml) An[ml] = *(const s16x8*)(an + ml * 1024);
#pragma unroll
            for (int ry = 0; ry < 7; ++ry) {
                s16x8 B = *(const s16x8*)(bp + ry * 2048);   // immediate offsets
#pragma unroll
                for (int ml = 0; ml < 4; ++ml)
                    acc[ml][ry] = __builtin_amdgcn_mfma_f32_16x16x32_bf16(Ac[ml], B, acc[ml][ry], 0, 0, 0);
            }
#pragma unroll
            for (int ml = 0; ml < 4; ++ml) Ac[ml] = An[ml];
        }

        // epilogue: affine -> pool (shfl 1,8) -> ReLU -> store into xs3 (disjoint array, no extra barrier)
        int m = lx >> 1;
        int xp = cb * 4 + m;
        bool keep = (dy == 0) && ((lx & 1) == 0) && (xp < 7);
#pragma unroll
        for (int ml = 0; ml < 4; ++ml) {
            int oc0 = oh * 64 + ml * 16 + quad * 4;
            float2 abv[4];
#pragma unroll
            for (int r = 0; r < 4; ++r) abv[r] = ab2[oc0 + r];
#pragma unroll
            for (int ry = 0; ry < 7; ++ry) {
                float pv[4];
#pragma unroll
                for (int r = 0; r < 4; ++r) {
                    float v = acc[ml][ry][r] * abv[r].x + abv[r].y;
                    v = fmaxf(v, __shfl_xor(v, 1));
                    v = fmaxf(v, __shfl_xor(v, 8));
                    pv[r] = fmaxf(v, 0.f);
                }
                if (keep) {
                    uint2 pk;
                    pk.x = pack2bf(pv[0], pv[1]);
                    pk.y = pack2bf(pv[2], pv[3]);
                    int blk3 = (oc0 >> 3) ^ (((xp + 1) & 7) << 1);
                    *(uint2*)&xs3[(((ry + 1) * 8 + (xp + 1)) * 16 + blk3) * 8 + (oc0 & 7)] = pk;
                }
            }
        }
    }
    __syncthreads();

    // ---- stage C: conv3 (128->256) MFMA. Waves: oc-quarter each, all 3 pooled rows. 48 AGPR. ----
    int oq = wid;                            // oc quarter (64 ocs, 4 frags of 16)

    f32x4 acc3[4][3];
    {
        f32x4 z = {0.f, 0.f, 0.f, 0.f};
#pragma unroll
        for (int ml = 0; ml < 4; ++ml)
#pragma unroll
            for (int nt = 0; nt < 3; ++nt) acc3[ml][nt] = z;
    }

    {
        const short* aC0 = wT3 + oq * 8192 + n16 * 128 + quad * 8;
        s16x8 Ac[4], An[4];
#pragma unroll
        for (int ml = 0; ml < 4; ++ml) Ac[ml] = *(const s16x8*)(aC0 + ml * 2048);

#pragma unroll 1
        for (int it = 0; it < 36; ++it) {
            int kykx = it >> 2, kk = it & 3;
            int ky = kykx / 3, kx = kykx - 3 * ky;
            int y0 = dy + ky;
            int x0 = lx + kx;                // garbage lanes lx>=6 discarded
            int blk = (kk * 4 + quad) ^ ((x0 & 7) << 1);
            const short* bp = &xs3[((y0 * 8 + x0) * 16 + blk) * 8];
            int itn = (it < 35) ? it + 1 : 0;
            const short* an = aC0 + (itn >> 2) * 32768 + (itn & 3) * 32;
#pragma unroll
            for (int ml = 0; ml < 4; ++ml) An[ml] = *(const s16x8*)(an + ml * 2048);
            s16x8 B0 = *(const s16x8*)(bp);            // pooled row 0 (y_in = y0)
            s16x8 B1 = *(const s16x8*)(bp + 2048);     // pooled row 1 (y_in = y0+2)
            s16x8 B2 = *(const s16x8*)(bp + 4096);     // pooled row 2 (y_in = y0+4)
#pragma unroll
            for (int ml = 0; ml < 4; ++ml) {
                acc3[ml][0] = __builtin_amdgcn_mfma_f32_16x16x32_bf16(Ac[ml], B0, acc3[ml][0], 0, 0, 0);
                acc3[ml][1] = __builtin_amdgcn_mfma_f32_16x16x32_bf16(Ac[ml], B1, acc3[ml][1], 0, 0, 0);
                acc3[ml][2] = __builtin_amdgcn_mfma_f32_16x16x32_bf16(Ac[ml], B2, acc3[ml][2], 0, 0, 0);
            }
#pragma unroll
            for (int ml = 0; ml < 4; ++ml) Ac[ml] = An[ml];
        }
    }

    // epilogue: affine -> pool -> relu -> dot with fc1_w row 1
    float vacc = 0.f;
    {
        int m = lx >> 1;
        bool keep = (dy == 0) && ((lx & 1) == 0) && (m < 3);
        const float* fc1w1 = fc1w + 2304;    // row 1 (only row that matters)
#pragma unroll
        for (int ml = 0; ml < 4; ++ml) {
            int oc0 = oq * 64 + ml * 16 + quad * 4;
            float2 abv[4];
#pragma unroll
            for (int r = 0; r < 4; ++r) abv[r] = ab3[oc0 + r];
#pragma unroll
            for (int nt = 0; nt < 3; ++nt) {
#pragma unroll
                for (int r = 0; r < 4; ++r) {
                    float v = acc3[ml][nt][r] * abv[r].x + abv[r].y;
                    v = fmaxf(v, __shfl_xor(v, 1));
                    v = fmaxf(v, __shfl_xor(v, 8));
                    v = fmaxf(v, 0.f);
                    if (keep) vacc += v * fc1w1[(oc0 + r) * 9 + nt * 3 + m];
                }
            }
        }
    }
#pragma unroll
    for (int s = 1; s < 64; s <<= 1) vacc += __shfl_xor(vacc, s);
    if (lane == 0) red[wid] = vacc;
    __syncthreads();
    if (t == 0) {
        float v = red[0] + red[1] + red[2] + red[3] + qc[5];
        // quantum circuit closed form: <Z0 Z1> = cos(h[:,1]) * cos(qp[1])
        float q = cosf(v) * qc[4];
        float l0 = q * qc[0] + qc[2];
        float l1 = q * qc[1] + qc[3];
        float mx = fmaxf(l0, l1);
        float lse = mx + logf(__expf(l0 - mx) + __expf(l1 - mx));
        out[b * 2 + 0] = l0 - lse;
        out[b * 2 + 1] = l1 - lse;
    }
}

extern "C" void kernel_launch(void* const* d_in, const int* in_sizes, int n_in,
                              void* d_out, int out_size, void* d_ws, size_t ws_size,
                              hipStream_t stream)
{
    const float* x    = (const float*)d_in[0];
    const float* c1w  = (const float*)d_in[1];
    const float* c1b  = (const float*)d_in[2];
    const float* c2w  = (const float*)d_in[3];
    const float* c2b  = (const float*)d_in[4];
    const float* c3w  = (const float*)d_in[5];
    const float* c3b  = (const float*)d_in[6];
    const float* g1   = (const float*)d_in[7];
    const float* b1   = (const float*)d_in[8];
    const float* m1   = (const float*)d_in[9];
    const float* v1   = (const float*)d_in[10];
    const float* g2   = (const float*)d_in[11];
    const float* b2   = (const float*)d_in[12];
    const float* m2   = (const float*)d_in[13];
    const float* v2   = (const float*)d_in[14];
    const float* g3   = (const float*)d_in[15];
    const float* b3   = (const float*)d_in[16];
    const float* m3   = (const float*)d_in[17];
    const float* v3   = (const float*)d_in[18];
    const float* fc1w = (const float*)d_in[19];
    const float* fc1b = (const float*)d_in[20];
    const float* qp   = (const float*)d_in[21];
    const float* fc2w = (const float*)d_in[22];
    const float* fc2b = (const float*)d_in[23];
    const float* fc3w = (const float*)d_in[24];
    const float* fc3b = (const float*)d_in[25];
    float* out = (float*)d_out;
    char* ws = (char*)d_ws;

    short*  wT2 = (short*)(ws + OFF_W2);
    short*  wT3 = (short*)(ws + OFF_W3);
    float2* ab1 = (float2*)(ws + OFF_AB1);
    float2* ab2 = (float2*)(ws + OFF_AB2);
    float2* ab3 = (float2*)(ws + OFF_AB3);
    float*  qc  = (float*)(ws + OFF_Q);

    int B = in_sizes[0] / 784;               // 8192

    prep_k<<<1152, 256, 0, stream>>>(c2w, c3w, c1b, g1, b1, m1, v1,
                                     c2b, g2, b2, m2, v2, c3b, g3, b3, m3, v3,
                                     fc1b, qp, fc2w, fc2b, fc3w, fc3b,
                                     wT2, wT3, ab1, ab2, ab3, qc);
    fused_k<<<B, 256, 0, stream>>>(x, c1w, ab1, ab2, ab3, wT2, wT3, fc1w, qc, out);
}